// Round 7
// baseline (79.245 us; speedup 1.0000x reference)
//
#include <hip/hip_runtime.h>
#include <math.h>

// Layout R7: ONE batch element per wave64.  Amp index p (8 bits):
// lane L = bits 7..2 (6 lane bits), pack axis = bit1 (wire 6), q = bit0
// (wire 7).  State: CR[2], CI[2] v2f; CR[q].x = amp(bit1=0), .y = amp(bit1=1).
// 8192 waves -> 8 waves/SIMD (vs 4 before).
//
// All packed math is NATIVE v2f (__builtin_elementwise_fma / shufflevector)
// so the backend forms v_pk_fma_f32 + op_sel itself and schedules freely.
//
// Lane-lane ring CNOTs (wires 0..4 -> lane bits k5..k1) are lazy GF(2)
// relabels; (5,6) = lane-ctrl pack-swap, (6,7) = pack-hi q-swap, (7,0) =
// q1-shuffle.  Maps computed offline (R parity-masks / V xor-masks on the
// 6 lane bits; wire w -> lane bit k=5-w):
//  C1 U:(32,32)(16,16)(8,8)(4,4)(2,2)(1,1)      (5,6)ctrl 63  (7,0)V 48
//  C2 U:(32,48)(48,24)(56,12)(60,6)(62,3)(63,1) ctrl 21  V 40
//  C3 U:(32,40)(16,20)(40,10)(20,5)(42,2)(21,1) ctrl 51  V 60
//  C4 U:(32,60)(48,30)(24,15)(12,7)(38,3)(51,1) ctrl 17  V 34
//  QCNN: w0(32,34) w1(16,17) w2(8,8) w3(4,4) w4(34,2) w5(17,1)
// Invariants verified: popc(R&V) odd per gate, popc(Rc&Vt) even per CRX.

typedef float v2f __attribute__((ext_vector_type(2)));

__device__ __forceinline__ v2f vfma(v2f a, v2f b, v2f c) {
  return __builtin_elementwise_fma(a, b, c);
}
__device__ __forceinline__ v2f vswap(v2f a) {
  return __builtin_shufflevector(a, a, 1, 0);
}
__device__ __forceinline__ v2f dup(float x) { return (v2f){x, x}; }

template <int M>
__device__ __forceinline__ float shxm(float v) {
  if constexpr (M == 1 || M == 2 || M == 3 || M == 7 || M == 8 || M == 15) {
    constexpr int ctrl = (M == 1) ? 0xB1 : (M == 2) ? 0x4E : (M == 3) ? 0x1B
                         : (M == 7) ? 0x141 : (M == 8) ? 0x128 : 0x140;
    return __int_as_float(__builtin_amdgcn_update_dpp(
        0, __float_as_int(v), ctrl, 0xF, 0xF, true));
  } else if constexpr (M < 32) {
    return __int_as_float(__builtin_amdgcn_ds_swizzle(
        __float_as_int(v), (M << 10) | 0x1F));
  } else {
    return __shfl_xor(v, M, 64);
  }
}
template <int M>
__device__ __forceinline__ v2f shf2(v2f a) {
  return (v2f){shxm<M>(a.x), shxm<M>(a.y)};
}

struct G1 { float r00, i00, r01, i01, r10, i10, r11, i11; };

// U = RZ@RY on a lane bit.
template <int RL, int VL>
__device__ __forceinline__ void u_lane(v2f (&CR)[2], v2f (&CI)[2], int l,
                                       float uAr, float uBi, float uAip,
                                       float uBrp) {
  const bool hi = (__popc(l & RL) & 1) != 0;
  const v2f cAr = dup(uAr), cBi = dup(uBi);
  const v2f cAi = dup(hi ? uAip : -uAip);
  const v2f cBr = dup(hi ? uBrp : -uBrp);
  v2f PR[2], PI[2];
#pragma unroll
  for (int q = 0; q < 2; ++q) { PR[q] = shf2<VL>(CR[q]); PI[q] = shf2<VL>(CI[q]); }
#pragma unroll
  for (int q = 0; q < 2; ++q) {
    v2f NR = vfma(-cBi, PI[q], vfma(cBr, PR[q], vfma(-cAi, CI[q], cAr * CR[q])));
    v2f NI = vfma(cBi, PR[q], vfma(cBr, PI[q], vfma(cAi, CR[q], cAr * CI[q])));
    CR[q] = NR; CI[q] = NI;
  }
}

// U on the pack axis (wire 6): swapped-half vectors, per-half coeff signs.
__device__ __forceinline__ void u_pack(v2f (&CR)[2], v2f (&CI)[2], float uAr,
                                       float uBi, float uAip, float uBrp) {
  const v2f Arv = dup(uAr), Biv = dup(uBi);
  const v2f Aiv = (v2f){-uAip, uAip};
  const v2f Brv = (v2f){-uBrp, uBrp};
#pragma unroll
  for (int q = 0; q < 2; ++q) {
    const v2f XR = CR[q], XI = CI[q], SR = vswap(XR), SI = vswap(XI);
    CR[q] = vfma(-Biv, SI, vfma(Brv, SR, vfma(-Aiv, XI, Arv * XR)));
    CI[q] = vfma(Biv, SR, vfma(Brv, SI, vfma(Aiv, XR, Arv * XI)));
  }
}

// generic 2x2 complex gate on bit0 (q pair), scalar coefficients.
__device__ __forceinline__ void g_pair(v2f (&CR)[2], v2f (&CI)[2], float g00r,
                                       float g00i, float g01r, float g01i,
                                       float g10r, float g10i, float g11r,
                                       float g11i) {
  const v2f LR = CR[0], LI = CI[0], HR = CR[1], HI = CI[1];
  CR[0] = vfma(dup(-g01i), HI, vfma(dup(g01r), HR, vfma(dup(-g00i), LI, dup(g00r) * LR)));
  CI[0] = vfma(dup(g01i), HR, vfma(dup(g01r), HI, vfma(dup(g00i), LR, dup(g00r) * LI)));
  CR[1] = vfma(dup(-g11i), HI, vfma(dup(g11r), HR, vfma(dup(-g10i), LI, dup(g10r) * LR)));
  CI[1] = vfma(dup(g11i), HR, vfma(dup(g11r), HI, vfma(dup(g10i), LR, dup(g10r) * LI)));
}

// ring CNOT (5,6): lane-parity ctrl, conditional pack-half swap.
template <int RL>
__device__ __forceinline__ void cnot_l_pack(v2f (&CR)[2], v2f (&CI)[2], int l) {
  const bool c = (__popc(l & RL) & 1) != 0;
#pragma unroll
  for (int q = 0; q < 2; ++q) {
    const v2f r = CR[q], i = CI[q];
    CR[q] = (v2f){c ? r.y : r.x, c ? r.x : r.y};
    CI[q] = (v2f){c ? i.y : i.x, c ? i.x : i.y};
  }
}

// ring CNOT (6,7): pack-hi ctrl -> swap hi halves of q0/q1.
__device__ __forceinline__ void cnot_pack_bit0(v2f (&CR)[2], v2f (&CI)[2]) {
  float t;
  t = CR[0].y; CR[0].y = CR[1].y; CR[1].y = t;
  t = CI[0].y; CI[0].y = CI[1].y; CI[1].y = t;
}

// ring CNOT (7,0): q=1 ctrl -> shuffle CR[1]/CI[1] by lane mask VL.
template <int VL>
__device__ __forceinline__ void cnot_bit0_lane(v2f (&CR)[2], v2f (&CI)[2]) {
  CR[1] = shf2<VL>(CR[1]); CI[1] = shf2<VL>(CI[1]);
}

// CRX lane-ctrl -> lane-target.
template <int RL, int VL>
__device__ __forceinline__ void crx_ll(v2f (&CR)[2], v2f (&CI)[2], int l,
                                       float co, float si) {
  const bool c = (__popc(l & RL) & 1) != 0;
  const v2f cc = dup(c ? co : 1.f), ss = dup(c ? si : 0.f);
  v2f PR[2], PI[2];
#pragma unroll
  for (int q = 0; q < 2; ++q) { PR[q] = shf2<VL>(CR[q]); PI[q] = shf2<VL>(CI[q]); }
#pragma unroll
  for (int q = 0; q < 2; ++q) {
    CR[q] = vfma(ss, PI[q], cc * CR[q]);
    CI[q] = vfma(-ss, PR[q], cc * CI[q]);
  }
}

// CRX lane-ctrl -> pack-axis target (5,6).
template <int RL>
__device__ __forceinline__ void crx_l_pack(v2f (&CR)[2], v2f (&CI)[2], int l,
                                           float co, float si) {
  const bool c = (__popc(l & RL) & 1) != 0;
  const v2f cc = dup(c ? co : 1.f), ss = dup(c ? si : 0.f);
#pragma unroll
  for (int q = 0; q < 2; ++q) {
    const v2f SR = vswap(CR[q]), SI = vswap(CI[q]);
    CR[q] = vfma(ss, SI, cc * CR[q]);
    CI[q] = vfma(-ss, SR, cc * CI[q]);
  }
}

// CRX with target bit0; cc/ss vectors support pack-ctrl ((1,co)/(0,si)).
__device__ __forceinline__ void crx_pair(v2f (&CR)[2], v2f (&CI)[2], v2f cc,
                                         v2f ss) {
  const v2f LR = CR[0], LI = CI[0], HR = CR[1], HI = CI[1];
  CR[0] = vfma(ss, HI, cc * LR);
  CI[0] = vfma(-ss, HR, cc * LI);
  CR[1] = vfma(ss, LI, cc * HR);
  CI[1] = vfma(-ss, LR, cc * HI);
}

// U3 on a lane bit.
template <int RL, int VL>
__device__ __forceinline__ void u3_lane(v2f (&CR)[2], v2f (&CI)[2], int l,
                                        const G1& g) {
  const bool hi = (__popc(l & RL) & 1) != 0;
  const v2f Ar = dup(hi ? g.r11 : g.r00), Ai = dup(hi ? g.i11 : g.i00);
  const v2f Br = dup(hi ? g.r10 : g.r01), Bi = dup(hi ? g.i10 : g.i01);
  v2f PR[2], PI[2];
#pragma unroll
  for (int q = 0; q < 2; ++q) { PR[q] = shf2<VL>(CR[q]); PI[q] = shf2<VL>(CI[q]); }
#pragma unroll
  for (int q = 0; q < 2; ++q) {
    v2f NR = vfma(-Bi, PI[q], vfma(Br, PR[q], vfma(-Ai, CI[q], Ar * CR[q])));
    v2f NI = vfma(Bi, PR[q], vfma(Br, PI[q], vfma(Ai, CR[q], Ar * CI[q])));
    CR[q] = NR; CI[q] = NI;
  }
}

__device__ __forceinline__ G1 load_g1(const float* __restrict__ cs, int k) {
  const float* p = cs + 22 + 8 * k;
  G1 g;
  g.r00 = p[0]; g.i00 = p[1]; g.r01 = p[2]; g.i01 = p[3];
  g.r10 = p[4]; g.i10 = p[5]; g.r11 = p[6]; g.i11 = p[7];
  return g;
}

// prep: ws[0..21] = (co,si) for crx[0..10]; ws[22+8k..] = G1 for u3 gate k.
__global__ void prep_kernel(const float* __restrict__ crx,
                            const float* __restrict__ u3p,
                            float* __restrict__ ws) {
  const int t = threadIdx.x;
  if (t < 11) {
    float s, c;
    sincosf(0.5f * crx[t], &s, &c);
    ws[2 * t] = c; ws[2 * t + 1] = s;
  } else if (t >= 16 && t < 23) {
    const int k = t - 16;
    float st, ct, sp, cp, sl, cl;
    sincosf(0.5f * u3p[3 * k], &st, &ct);
    sincosf(u3p[3 * k + 1], &sp, &cp);
    sincosf(u3p[3 * k + 2], &sl, &cl);
    float* o = ws + 22 + 8 * k;
    o[0] = ct;            o[1] = 0.f;
    o[2] = -cl * st;      o[3] = -sl * st;
    o[4] = cp * st;       o[5] = sp * st;
    o[6] = (cp * cl - sp * sl) * ct;
    o[7] = (sp * cl + cp * sl) * ct;
  }
}

__global__ __launch_bounds__(256, 8) void qcnn_kernel(
    const float* __restrict__ theta, const float* __restrict__ phi,
    const float* __restrict__ cs, float* __restrict__ out, int nbatch) {
  const int lane = threadIdx.x & 63;
  int b = blockIdx.x * 4 + (threadIdx.x >> 6);
  if (b >= nbatch) b = nbatch - 1;

  v2f CR[2], CI[2];
  CR[0] = (v2f){lane == 0 ? 1.f : 0.f, 0.f};
  CR[1] = dup(0.f); CI[0] = dup(0.f); CI[1] = dup(0.f);

  float sth, cth, sph, cph;
  __sincosf(0.5f * theta[b], &sth, &cth);
  __sincosf(0.5f * phi[b], &sph, &cph);
  const float uAr = cph * cth, uBi = sph * sth;
  const float uAip = sph * cth, uBrp = cph * sth;

#define UL(RL, VL) u_lane<RL, VL>(CR, CI, lane, uAr, uBi, uAip, uBrp)
#define UREST() do { u_pack(CR, CI, uAr, uBi, uAip, uBrp); \
                     g_pair(CR, CI, uAr, -uAip, -uBrp, uBi, \
                            uBrp, uBi, uAr, uAip); } while (0)
#define RING(RLC, VL70) do { cnot_l_pack<RLC>(CR, CI, lane); \
                             cnot_pack_bit0(CR, CI); \
                             cnot_bit0_lane<VL70>(CR, CI); } while (0)

  // cycle 1
  UL(32, 32); UL(16, 16); UL(8, 8);   UL(4, 4);  UL(2, 2);  UL(1, 1);
  UREST(); RING(63, 48);
  // cycle 2
  UL(32, 48); UL(48, 24); UL(56, 12); UL(60, 6); UL(62, 3); UL(63, 1);
  UREST(); RING(21, 40);
  // cycle 3
  UL(32, 40); UL(16, 20); UL(40, 10); UL(20, 5); UL(42, 2); UL(21, 1);
  UREST(); RING(51, 60);
  // cycle 4
  UL(32, 60); UL(48, 30); UL(24, 15); UL(12, 7); UL(38, 3); UL(51, 1);
  UREST(); RING(17, 34);
#undef RING
#undef UREST
#undef UL

  // ---- QCNN section (maps: w0(32,34) w1(16,17) w2(8,8) w3(4,4) w4(34,2)
  // w5(17,1); wire6 = pack axis, wire7 = bit0) ----
#define LD(k) const float co##k = cs[2 * k], si##k = cs[2 * k + 1]
  LD(0); crx_ll<32, 17>(CR, CI, lane, co0, si0);  // (0,1)
  LD(1); crx_ll<8, 4>(CR, CI, lane, co1, si1);    // (2,3)
  LD(2); crx_ll<34, 1>(CR, CI, lane, co2, si2);   // (4,5)
  LD(3); crx_pair(CR, CI, (v2f){1.f, co3}, (v2f){0.f, si3});  // (6,7)
  LD(4); crx_ll<16, 8>(CR, CI, lane, co4, si4);   // (1,2)
  LD(5); crx_ll<4, 2>(CR, CI, lane, co5, si5);    // (3,4)
  LD(6); crx_l_pack<17>(CR, CI, lane, co6, si6);  // (5,6)

  { G1 g = load_g1(cs, 0); u3_lane<16, 17>(CR, CI, lane, g); }  // wire 1
  { G1 g = load_g1(cs, 1); u3_lane<4, 4>(CR, CI, lane, g); }    // wire 3
  { G1 g = load_g1(cs, 2); u3_lane<17, 1>(CR, CI, lane, g); }   // wire 5
  { G1 g = load_g1(cs, 3);                                      // wire 7
    g_pair(CR, CI, g.r00, g.i00, g.r01, g.i01, g.r10, g.i10, g.r11, g.i11); }

  LD(7); crx_ll<16, 4>(CR, CI, lane, co7, si7);   // (1,3)
  LD(8);                                          // (5,7): lane ctrl 17
  {
    const bool c = (__popc(lane & 17) & 1) != 0;
    crx_pair(CR, CI, dup(c ? co8 : 1.f), dup(c ? si8 : 0.f));
  }
  LD(9); crx_ll<4, 1>(CR, CI, lane, co9, si9);    // (3,5)

  { G1 g = load_g1(cs, 4); u3_lane<4, 4>(CR, CI, lane, g); }    // wire 3
  { G1 g = load_g1(cs, 5);                                      // wire 7
    g_pair(CR, CI, g.r00, g.i00, g.r01, g.i01, g.r10, g.i10, g.r11, g.i11); }

  LD(10);                                         // (3,7): lane ctrl 4
  {
    const bool c = (__popc(lane & 4) & 1) != 0;
    crx_pair(CR, CI, dup(c ? co10 : 1.f), dup(c ? si10 : 0.f));
  }

  { G1 g = load_g1(cs, 6);                                      // wire 7
    g_pair(CR, CI, g.r00, g.i00, g.r01, g.i01, g.r10, g.i10, g.r11, g.i11); }
#undef LD

  // <Z_wire7>: sign = q bit; reduce over 64 lanes.
  const v2f T = vfma(CR[0], CR[0], CI[0] * CI[0])
              - vfma(CR[1], CR[1], CI[1] * CI[1]);
  float v = T.x + T.y;
  v += shxm<1>(v); v += shxm<2>(v); v += shxm<4>(v);
  v += shxm<8>(v); v += shxm<16>(v); v += shxm<32>(v);
  if (lane == 0) out[b] = fmaxf(v, 0.f);
}

extern "C" void kernel_launch(void* const* d_in, const int* in_sizes, int n_in,
                              void* d_out, int out_size, void* d_ws, size_t ws_size,
                              hipStream_t stream) {
  const float* theta = (const float*)d_in[0];
  const float* phi = (const float*)d_in[1];
  const float* crx = (const float*)d_in[2];
  const float* u3p = (const float*)d_in[3];
  float* out = (float*)d_out;
  float* ws = (float*)d_ws;
  const int nb = in_sizes[0];

  prep_kernel<<<1, 64, 0, stream>>>(crx, u3p, ws);

  const int elems_per_block = 4;  // 4 waves * 1 element
  dim3 block(256);
  dim3 grid((nb + elems_per_block - 1) / elems_per_block);
  qcnn_kernel<<<grid, block, 0, stream>>>(theta, phi, ws, out, nb);
}